// Round 18
// baseline (136.254 us; speedup 1.0000x reference)
//
#include <hip/hip_runtime.h>
#include <hip/hip_bf16.h>

#define NH 6
#define DIM 192
#define HW 192
#define M_TOK (HW*HW)
// SCALE*log2e and log2e
#define QSC 0.25503488f
#define L2E 1.4426950408889634f

typedef __attribute__((ext_vector_type(8))) __bf16 bf16x8;
typedef __attribute__((ext_vector_type(8))) short short8;
typedef __attribute__((ext_vector_type(4))) short s16x4;
typedef __attribute__((ext_vector_type(4))) float floatx4;

__device__ inline unsigned short f2bf(float f) {
    union { float f; unsigned int u; } v; v.f = f;
    unsigned int r = (v.u + 0x7FFFu + ((v.u >> 16) & 1u)) >> 16;
    return (unsigned short)r;
}
__device__ inline short f2bfh(float f) {
    __bf16 b = (__bf16)f;
    return __builtin_bit_cast(short, b);
}
__device__ inline float exp2fast(float x) {
#if __has_builtin(__builtin_amdgcn_exp2f)
    return __builtin_amdgcn_exp2f(x);
#else
    return exp2f(x);
#endif
}
// bf16x4 -> f32x4 (bit shift)
__device__ inline floatx4 bf4f(s16x4 b) {
    floatx4 f;
    #pragma unroll
    for (int r = 0; r < 4; r++) {
        union { unsigned u; float f; } v;
        v.u = ((unsigned)(unsigned short)b[r]) << 16;
        f[r] = v.f;
    }
    return f;
}

__device__ inline floatx4 mfma16(short8 a, short8 b, floatx4 c) {
    return __builtin_amdgcn_mfma_f32_16x16x32_bf16(
        __builtin_bit_cast(bf16x8, a), __builtin_bit_cast(bf16x8, b), c, 0, 0, 0);
}

template <int OFF>
__device__ inline s16x4 tr16(unsigned addr) {
    s16x4 r;
    asm volatile("ds_read_b64_tr_b16 %0, %1 offset:%2"
                 : "=&v"(r) : "v"(addr), "i"(OFF));
    return r;
}
template <int OFF>
__device__ inline s16x4 tr16m(unsigned addr) {
    s16x4 r;
    asm volatile("ds_read_b64_tr_b16 %0, %1 offset:%2"
                 : "=&v"(r) : "v"(addr), "i"(OFF) : "memory");
    return r;
}
template <int N>
__device__ __forceinline__ void wait_lgkm() {
    asm volatile("s_waitcnt lgkmcnt(%0)" :: "i"(N) : "memory");
}
template <int N>
__device__ __forceinline__ void wait_vm() {
    asm volatile("s_waitcnt vmcnt(%0)" :: "i"(N) : "memory");
}
__device__ __forceinline__ void bar_raw() {
    asm volatile("s_barrier" ::: "memory");
}
__device__ inline short8 cat8(s16x4 a, s16x4 b) {
    return __builtin_shufflevector(a, b, 0, 1, 2, 3, 4, 5, 6, 7);
}

// async global->LDS, 16B per lane; lds_off = wave-uniform LDS byte offset
__device__ __forceinline__ void gload16(const void* g, unsigned lds_off) {
    __builtin_amdgcn_global_load_lds(
        (const __attribute__((address_space(1))) unsigned int*)(uintptr_t)g,
        (__attribute__((address_space(3))) unsigned int*)(uintptr_t)lds_off,
        16, 0, 0);
}

// ---- side-work bodies ----
__device__ __forceinline__ void btfrag_body(int id, const int* __restrict__ rpi,
                                            const float* __restrict__ table,
                                            unsigned short* __restrict__ btf) {
    int lane = id & 63;
    int t = id >> 6;
    int kt = t % 36; t /= 36;
    int qt = t & 15; int hh = t >> 4;
    int k = kt * 16 + (lane & 15);
    int qb = qt * 16 + (lane >> 4) * 4;
    s16x4 v;
    #pragma unroll
    for (int r = 0; r < 4; r++)
        v[r] = f2bfh(table[rpi[(qb + r) * 576 + k] * NH + hh] * L2E);
    *(s16x4*)&btf[(size_t)id * 4] = v;
}

__device__ __forceinline__ void wcast_rest_body(int i2, const float* __restrict__ projw,
                                                const float* __restrict__ fc1w,
                                                const float* __restrict__ fc2w,
                                                unsigned short* __restrict__ wt_proj,
                                                unsigned short* __restrict__ wt_fc1,
                                                unsigned short* __restrict__ wt_fc2) {
    if (i2 < 36864) {
        int n = i2 / 192, k = i2 - n * 192;
        wt_proj[i2] = f2bf(projw[k * 192 + n]);
    } else if (i2 < 110592) {
        int i = i2 - 36864;
        int n = i / 192, k = i - n * 192;
        wt_fc1[i] = f2bf(fc1w[k * 384 + n]);
    } else {
        int i = i2 - 110592;
        int n = i / 384, k = i - n * 384;
        wt_fc2[i] = f2bf(fc2w[k * 192 + n]);
    }
}

// ---- prep: wcast-qkv + LayerNorm1 only (gates the qkv GEMM) ----
__global__ __launch_bounds__(256) void prep_kernel(
    const float* __restrict__ qkvw,
    const float* __restrict__ x, const float* __restrict__ n1g,
    const float* __restrict__ n1b,
    unsigned short* __restrict__ wt_qkv,
    unsigned short* __restrict__ xn) {
    int bid = blockIdx.x;
    if (bid < 432) {
        int id = bid * 256 + threadIdx.x;   // < 110592
        int n = id / 192, k = id - n * 192;
        wt_qkv[id] = f2bf(qkvw[k * 576 + n]);
    } else {
        int row = (bid - 432) * 4 + (threadIdx.x >> 6);
        int lane = threadIdx.x & 63;
        const float* r = x + (size_t)row * DIM;
        float x0 = r[lane], x1 = r[lane + 64], x2 = r[lane + 128];
        float s = x0 + x1 + x2;
        #pragma unroll
        for (int m = 32; m >= 1; m >>= 1) s += __shfl_xor(s, m);
        float mean = s * (1.f / 192.f);
        float d0 = x0 - mean, d1 = x1 - mean, d2 = x2 - mean;
        float v = d0 * d0 + d1 * d1 + d2 * d2;
        #pragma unroll
        for (int m = 32; m >= 1; m >>= 1) v += __shfl_xor(v, m);
        float rstd = rsqrtf(v * (1.f / 192.f) + 1e-5f);
        unsigned short* o = xn + (size_t)row * DIM;
        o[lane]       = f2bf(d0 * rstd * n1g[lane]       + n1b[lane]);
        o[lane + 64]  = f2bf(d1 * rstd * n1g[lane + 64]  + n1b[lane + 64]);
        o[lane + 128] = f2bf(d2 * rstd * n1g[lane + 128] + n1b[lane + 128]);
    }
}

// ---- qkv GEMM v2: A staged once, 18 reg-prefetched weight slabs ----
// Block = 64 tokens (bx<576), 4 waves; wave w owns rows w*16..w*16+15.
// LDS: sA [64][192] as 2 slabs [64][104] (26.6KB) + sB [64][104] (13.3KB)
// = 39.9KB. Loop bn=0..8 x ks=0..1: weight slab [64][96] prefetched to regs
// one stage ahead; raw s_barrier + counted vm/lgkm waits (mega-v2 schedule).
// Epilogue per bn: planar qkv write [part*6+head][tok][32], Q scaled by QSC.
// Extra blocks (bx>=576): btfrag + wcast proj/fc1/fc2 (later consumers only).
__global__ __launch_bounds__(256, 3) void qkv_kernel(
    const unsigned short* __restrict__ A,      // xn [M_TOK][192]
    const unsigned short* __restrict__ Wt,     // wt_qkv [576][192]
    const float* __restrict__ bias,
    unsigned short* __restrict__ outp,
    const int* __restrict__ rpi, const float* __restrict__ table,
    unsigned short* __restrict__ btf,
    const float* __restrict__ projw, const float* __restrict__ fc1w,
    const float* __restrict__ fc2w,
    unsigned short* __restrict__ wt_proj, unsigned short* __restrict__ wt_fc1,
    unsigned short* __restrict__ wt_fc2) {
    int bx = blockIdx.x;
    if (bx >= 576) {
        int extra = bx - 576;
        if (extra < 864) {
            btfrag_body(extra * 256 + threadIdx.x, rpi, table, btf);
        } else if (extra < 1584) {
            wcast_rest_body((extra - 864) * 256 + threadIdx.x,
                            projw, fc1w, fc2w, wt_proj, wt_fc1, wt_fc2);
        }
        return;
    }
    __shared__ __align__(16) short sA[13312];  // 2 slabs [64][104]
    __shared__ __align__(16) short sB[6656];   // weight slab [64][104]
    int tid = threadIdx.x;
    int w = tid >> 6, lane = tid & 63;
    int bm = bx;
    int lr = lane & 15, h = lane >> 4;

    short8 rg0, rg1, rg2;
    auto loadreg96 = [&](const unsigned short* base) {
        #pragma unroll
        for (int k = 0; k < 3; k++) {
            int d = (k * 256 + tid) * 16;
            int r = d / 192, cc = (d - r * 192) >> 1;
            short8 v = *(const short8*)&base[r * 192 + cc];
            if (k == 0) rg0 = v; else if (k == 1) rg1 = v; else rg2 = v;
        }
    };
    auto write96 = [&]() {
        #pragma unroll
        for (int k = 0; k < 3; k++) {
            int d = (k * 256 + tid) * 16;
            int r = d / 192, cc = (d - r * 192) >> 1;
            *(short8*)&sB[r * 104 + cc] = (k == 0) ? rg0 : (k == 1) ? rg1 : rg2;
        }
    };

    {   // stage A tile [64][192] into sA (2 slabs) via gload_lds
        unsigned ldsA = (unsigned)(uintptr_t)&sA[0];
        for (int W = w; W < 26; W += 4) {
            int o = W * 1024 + lane * 16;
            int sl = o / 13312;
            int o2 = o - sl * 13312;
            int r = o2 / 208;
            int c = (o2 - r * 208) >> 4; c = c < 12 ? c : 11;
            int col = sl * 96 + c * 8;
            gload16(&A[(size_t)(bm * 64 + r) * 192 + col],
                    ldsA + (unsigned)(W * 1024));
        }
    }
    loadreg96(Wt);                       // (bn0, ks0)

    int rowbase = bm * 64 + w * 16 + h * 4;
    for (int bn = 0; bn < 9; bn++) {
        floatx4 acc[4];
        #pragma unroll
        for (int ni = 0; ni < 4; ni++) acc[ni] = (floatx4){0.f, 0.f, 0.f, 0.f};

        #pragma unroll
        for (int ks = 0; ks < 2; ks++) {
            int s = bn * 2 + ks;
            bar_raw();
            wait_vm<0>();
            __builtin_amdgcn_sched_barrier(0);
            write96();
            if (s < 17) {
                int ns = s + 1;
                loadreg96(Wt + (size_t)((ns >> 1) * 64) * 192 + (ns & 1) * 96);
            }
            wait_lgkm<0>();
            __builtin_amdgcn_sched_barrier(0);
            bar_raw();
            const short* Ap = sA + ks * 6656;
            #pragma unroll
            for (int kk = 0; kk < 3; kk++) {
                int kc = (kk * 4 + h) * 8;
                short8 a = *(const short8*)&Ap[(w * 16 + lr) * 104 + kc];
                #pragma unroll
                for (int ni = 0; ni < 4; ni++) {
                    short8 b = *(const short8*)&sB[(ni * 16 + lr) * 104 + kc];
                    acc[ni] = mfma16(a, b, acc[ni]);
                }
            }
        }

        // epilogue for this bn: planar write
        #pragma unroll
        for (int ni = 0; ni < 4; ni++) {
            int c = bn * 64 + ni * 16 + lr;
            float bv = bias[c];
            int part = c / 192;
            int rem = c - part * 192;
            int hd = rem >> 5, d = rem & 31;
            #pragma unroll
            for (int j = 0; j < 4; j++) {
                float v = acc[ni][j] + bv;
                if (part == 0) v *= QSC;
                outp[((size_t)(part * 6 + hd) * M_TOK + rowbase + j) * 32 + d] = f2bf(v);
            }
        }
    }
}

// ---- MEGA v2: proj + res + LN2 + fc1 + GELU + fc2 + add, reg-prefetched ----
__global__ __launch_bounds__(256, 3) void mega_kernel(
    const unsigned short* __restrict__ Aop,    // attn_o planar [6][M_TOK][32]
    const unsigned short* __restrict__ Wp,     // wt_proj [192][192]
    const unsigned short* __restrict__ W1,     // wt_fc1  [384][192]
    const unsigned short* __restrict__ W2,     // wt_fc2  [192][384]
    const float* __restrict__ pb,
    const float* __restrict__ b1,
    const float* __restrict__ b2f,
    const float* __restrict__ res,
    const float* __restrict__ g2, const float* __restrict__ bb2,
    float* __restrict__ outp) {
    __shared__ __align__(16) short sA[13312];  // 2 slabs of [64][104] (attn_o -> ln)
    __shared__ __align__(16) short sH[4608];   // [64][72] h quarter
    __shared__ __align__(16) short sB[6656];   // weight slab [64][104] or [64][72]
    int tid = threadIdx.x;
    int w = tid >> 6, lane = tid & 63;
    int bm = blockIdx.x;
    int lr = lane & 15, h = lane >> 4;
    int lrow0 = w * 16 + h * 4;
    int row0 = bm * 64 + lrow0;

    floatx4 x2a[12];
    #pragma unroll
    for (int t = 0; t < 12; t++) x2a[t] = (floatx4){0.f, 0.f, 0.f, 0.f};

    short8 rg0, rg1, rg2;
    auto loadreg96 = [&](const unsigned short* base) {
        #pragma unroll
        for (int k = 0; k < 3; k++) {
            int d = (k * 256 + tid) * 16;
            int r = d / 192, cc = (d - r * 192) >> 1;
            short8 v = *(const short8*)&base[r * 192 + cc];
            if (k == 0) rg0 = v; else if (k == 1) rg1 = v; else rg2 = v;
        }
    };
    auto write96 = [&]() {
        #pragma unroll
        for (int k = 0; k < 3; k++) {
            int d = (k * 256 + tid) * 16;
            int r = d / 192, cc = (d - r * 192) >> 1;
            *(short8*)&sB[r * 104 + cc] = (k == 0) ? rg0 : (k == 1) ? rg1 : rg2;
        }
    };
    auto loadreg64 = [&](const unsigned short* base) {
        #pragma unroll
        for (int k = 0; k < 2; k++) {
            int d = (k * 256 + tid) * 16;
            int r = d / 128, cc = (d - r * 128) >> 1;
            short8 v = *(const short8*)&base[r * 384 + cc];
            if (k == 0) rg0 = v; else rg1 = v;
        }
    };
    auto write64 = [&]() {
        #pragma unroll
        for (int k = 0; k < 2; k++) {
            int d = (k * 256 + tid) * 16;
            int r = d / 128, cc = (d - r * 128) >> 1;
            *(short8*)&sB[r * 72 + cc] = (k == 0) ? rg0 : rg1;
        }
    };

    auto comp96 = [&](floatx4* acc, const short* Ap) {
        #pragma unroll
        for (int kk = 0; kk < 3; kk++) {
            int kc = (kk * 4 + h) * 8;
            short8 a = *(const short8*)&Ap[(w * 16 + lr) * 104 + kc];
            #pragma unroll
            for (int ni = 0; ni < 4; ni++) {
                short8 b = *(const short8*)&sB[(ni * 16 + lr) * 104 + kc];
                acc[ni] = mfma16(a, b, acc[ni]);
            }
        }
    };
    auto comp64 = [&](floatx4* acc) {
        #pragma unroll
        for (int kk = 0; kk < 2; kk++) {
            int kc = (kk * 4 + h) * 8;
            short8 a = *(const short8*)&sH[(w * 16 + lr) * 72 + kc];
            #pragma unroll
            for (int ni = 0; ni < 4; ni++) {
                short8 b = *(const short8*)&sB[(ni * 16 + lr) * 72 + kc];
                acc[ni] = mfma16(a, b, acc[ni]);
            }
        }
    };

#define SCH __builtin_amdgcn_sched_barrier(0)
#define ST96(LOADER, ACC, AP) \
    bar_raw(); wait_vm<0>(); SCH; write96(); LOADER; wait_lgkm<0>(); SCH; \
    bar_raw(); comp96(ACC, AP);
#define ST96F(LOADER, ACC, AP) \
    wait_vm<0>(); SCH; write96(); LOADER; wait_lgkm<0>(); SCH; \
    bar_raw(); comp96(ACC, AP);
#define ST64(LOADER, ACC) \
    bar_raw(); wait_vm<0>(); SCH; write64(); LOADER; wait_lgkm<0>(); SCH; \
    bar_raw(); comp64(ACC);

    {   // stage attn_o tile [64][192] into sA (2 slabs) via gload_lds
        unsigned ldsA = (unsigned)(uintptr_t)&sA[0];
        for (int W = w; W < 26; W += 4) {
            int o = W * 1024 + lane * 16;
            int sl = o / 13312;
            int o2 = o - sl * 13312;
            int r = o2 / 208;
            int c = (o2 - r * 208) >> 4; c = c < 12 ? c : 11;
            int col = sl * 96 + c * 8;
            int hd = col >> 5, d = col & 31;
            gload16(&Aop[((size_t)hd * M_TOK + bm * 64 + r) * 32 + d],
                    ldsA + (unsigned)(W * 1024));
        }
    }
    loadreg96(Wp);                                     // proj ks0 g0

    // ---- proj: 6 stages ----
    ST96F(loadreg96(Wp + 64 * 192),        &x2a[0], sA);          // ks0 g0
    ST96(loadreg96(Wp + 128 * 192),        &x2a[4], sA);          // ks0 g1
    ST96(loadreg96(Wp + 96),               &x2a[8], sA);          // ks0 g2
    ST96(loadreg96(Wp + 64 * 192 + 96),    &x2a[0], sA + 6656);   // ks1 g0
    ST96(loadreg96(Wp + 128 * 192 + 96),   &x2a[4], sA + 6656);   // ks1 g1
    ST96(loadreg96(W1),                    &x2a[8], sA + 6656);   // ks1 g2

    // ---- proj epilogue: x2 = acc + pb + res; LN2 -> sA (own rows) ----
    {
        float s1[4] = {0.f, 0.f, 0.f, 0.f}, s2[4] = {0.f, 0.f, 0.f, 0.f};
        #pragma unroll
        for (int t = 0; t < 12; t++) {
            int c = t * 16 + lr;
            float bv = pb[c];
            #pragma unroll
            for (int j = 0; j < 4; j++) {
                size_t idx = (size_t)(row0 + j) * 192 + c;
                float v = x2a[t][j] + bv + res[idx];
                x2a[t][j] = v;
                s1[j] += v;
                s2[j] += v * v;
            }
        }
        #pragma unroll
        for (int mask = 1; mask <= 8; mask <<= 1) {
            #pragma unroll
            for (int j = 0; j < 4; j++) {
                s1[j] += __shfl_xor(s1[j], mask);
                s2[j] += __shfl_xor(s2[j], mask);
            }
        }
        float mean[4], rstd[4];
        #pragma unroll
        for (int j = 0; j < 4; j++) {
            mean[j] = s1[j] * (1.f / 192.f);
            float var = s2[j] * (1.f / 192.f) - mean[j] * mean[j];
            rstd[j] = rsqrtf(var + 1e-5f);
        }
        #pragma unroll
        for (int t = 0; t < 12; t++) {
            int c = t * 16 + lr;
            float gw = g2[c], bw = bb2[c];
            int slab = t / 6;
            int cc = c - slab * 96;
            #pragma unroll
            for (int j = 0; j < 4; j++) {
                float lnv = (x2a[t][j] - mean[j]) * rstd[j] * gw + bw;
                sA[slab * 6656 + (lrow0 + j) * 104 + cc] = f2bfh(lnv);
            }
        }
    }

    // ---- MLP: per 64-col h-group: fc1 ks0, fc1 ks1, gelu, fc2 g0..g2 ----
    for (int hg = 0; hg < 6; hg++) {
        floatx4 ha[4];
        #pragma unroll
        for (int ni = 0; ni < 4; ni++) ha[ni] = (floatx4){0.f, 0.f, 0.f, 0.f};

        ST96(loadreg96(W1 + (size_t)(hg * 64) * 192 + 96), ha, sA);         // fc1 ks0
        ST96(loadreg64(W2 + hg * 64),                      ha, sA + 6656);  // fc1 ks1

        // gelu + bias -> sH (own rows)
        #pragma unroll
        for (int ni = 0; ni < 4; ni++) {
            int hc = hg * 64 + ni * 16 + lr;
            float bv = b1[hc];
            #pragma unroll
            for (int j = 0; j < 4; j++) {
                float v = ha[ni][j] + bv;
                float gl = 0.5f * v * (1.f + erff(v * 0.70710678118654752f));
                sH[(lrow0 + j) * 72 + ni * 16 + lr] = f2bfh(gl);
            }
        }

        ST64(loadreg64(W2 + (size_t)64 * 384 + hg * 64),  &x2a[0]);   // fc2 g0
        ST64(loadreg64(W2 + (size_t)128 * 384 + hg * 64), &x2a[4]);   // fc2 g1
        if (hg < 5) {
            ST64(loadreg96(W1 + (size_t)((hg + 1) * 64) * 192), &x2a[8]);
        } else {
            ST64(, &x2a[8]);
        }
    }
#undef ST96
#undef ST96F
#undef ST64
#undef SCH

    // ---- final: out = x2 + mlp + fc2b ----
    #pragma unroll
    for (int t = 0; t < 12; t++) {
        int c = t * 16 + lr;
        float bv = b2f[c];
        #pragma unroll
        for (int j = 0; j < 4; j++) {
            size_t idx = (size_t)(row0 + j) * 192 + c;
            outp[idx] = x2a[t][j] + bv;
        }
    }
}

// ---- MFMA windowed attention: r11-exact two-phase structure, planar QKV ----
__global__ __launch_bounds__(256, 3) void attn_mfma_kernel(
    const unsigned short* __restrict__ qkv,
    const unsigned short* __restrict__ btf,
    unsigned short* __restrict__ out) {
    __shared__ __align__(16) short sK[2][2304];
    __shared__ __align__(16) short sV[2][2048];
    __shared__ __align__(16) short sPt[4][4096];
    int win = blockIdx.x, head = blockIdx.y;
    int iy = win / 12, ix = win % 12;
    int tid = threadIdx.x;
    int w = tid >> 6, lane = tid & 63;
    int m = lane & 15, h = lane >> 4;

    const unsigned short* Qp = qkv + (size_t)head * M_TOK * 32;
    const unsigned short* Kp = qkv + (size_t)(6 + head) * M_TOK * 32;

    short8 qf[4];
    #pragma unroll
    for (int i = 0; i < 4; i++) {
        int wy = w * 4 + i;
        size_t tok = (size_t)(iy * 16 + wy) * HW + ix * 16 + m;
        qf[i] = *(const short8*)&Qp[tok * 32 + h * 8];
    }

    short ob = (m == 0) ? (short)0x3F80 : (short)0;
    short8 bones = {ob, ob, ob, ob, ob, ob, ob, ob};

    floatx4 oacc[4][2];
    floatx4 lacc[4];
    #pragma unroll
    for (int i = 0; i < 4; i++) {
        lacc[i] = (floatx4){0.f, 0.f, 0.f, 0.f};
        oacc[i][0] = (floatx4){0.f, 0.f, 0.f, 0.f};
        oacc[i][1] = (floatx4){0.f, 0.f, 0.f, 0.f};
    }

    int skey = tid >> 2, dq = tid & 3;
    short* kdst = &sK[0][skey * 36 + dq * 8];
    short* vdst = &sV[0][(dq >> 1) * 1024 + (skey >> 2) * 64 + (skey & 3) * 16 + (dq & 1) * 8];

    auto fetch = [&](int c, short8& kv, short8& vv) {
        int key = c * 64 + skey;
        int oy = key / 24, ox = key - (key / 24) * 24;
        int gy = iy * 16 - 4 + oy, gx = ix * 16 - 4 + ox;
        kv = (short8){0,0,0,0,0,0,0,0};
        vv = (short8){0,0,0,0,0,0,0,0};
        if (gy >= 0 && gy < HW && gx >= 0 && gx < HW) {
            const unsigned short* p = &Kp[((size_t)gy * HW + gx) * 32 + dq * 8];
            kv = *(const short8*)p;
            vv = *(const short8*)(p + 6 * M_TOK * 32);
        }
    };

    {   // stage chunk 0 into buffer 0
        short8 kv, vv;
        fetch(0, kv, vv);
        *(short8*)kdst = kv;
        *(short8*)vdst = vv;
    }

    unsigned sPbase = (unsigned)(uintptr_t)&sPt[w][0];
    unsigned sPa = sPbase + 8 * m + 256 * h;
    unsigned sVa0 = (unsigned)(uintptr_t)&sV[0][0] + 8 * m + 256 * h;
    char* sPwb = (char*)&sPt[w][0] + 128 * (m >> 2) + 32 * (m & 3) + 8 * h;

    for (int c = 0; c < 9; c++) {
        __syncthreads();
        int cur = c & 1;
        short8 knx, vnx;
        bool more = (c < 8);
        if (more) fetch(c + 1, knx, vnx);

        const short* sKc = sK[cur];
        short8 kfrag[4];
        #pragma unroll
        for (int kt = 0; kt < 4; kt++)
            kfrag[kt] = *(const short8*)&sKc[(kt * 16 + m) * 36 + h * 8];

        const unsigned short* bb = btf + ((((size_t)head * 16 + w * 4) * 36 + c * 4) * 64 + lane) * 4;

        #pragma unroll
        for (int i = 0; i < 4; i++) {
            floatx4 s[4];
            #pragma unroll
            for (int kt = 0; kt < 4; kt++)
                s[kt] = bf4f(*(const s16x4*)&bb[(size_t)(i * 36 + kt) * 256]);
            #pragma unroll
            for (int kt = 0; kt < 4; kt++)
                s[kt] = mfma16(qf[i], kfrag[kt], s[kt]);
            #pragma unroll
            for (int kt = 0; kt < 4; kt++) {
                s16x4 pk;
                #pragma unroll
                for (int r = 0; r < 4; r++)
                    pk[r] = f2bfh(exp2fast(s[kt][r]));
                *(s16x4*)(sPwb + i * 2048 + kt * 512) = pk;
            }
        }

        unsigned sVa = sVa0 + cur * 4096;
        short8 vb[4];
        {
            s16x4 lo0 = tr16<0>(sVa),    hi0 = tr16<128>(sVa);
            s16x4 lo1 = tr16<2048>(sVa), hi1 = tr16<2176>(sVa);
            s16x4 lo2 = tr16<1024>(sVa), hi2 = tr16<1152>(sVa);
            s16x4 lo3 = tr16<3072>(sVa), hi3 = tr16<3200>(sVa);
            vb[0] = cat8(lo0, hi0);
            vb[1] = cat8(lo1, hi1);
            vb[2] = cat8(lo2, hi2);
            vb[3] = cat8(lo3, hi3);
        }
        s16x4 pl0 = tr16m<0>(sPa),    ph0 = tr16m<128>(sPa);
        s16x4 pl1 = tr16m<1024>(sPa), ph1 = tr16m<1152>(sPa);
        #pragma unroll
        for (int i = 0; i < 4; i++) {
            s16x4 nl0, nh0, nl1, nh1;
            if (i < 3) {
                unsigned a = sPa + (unsigned)((i + 1) * 2048);
                nl0 = tr16m<0>(a);    nh0 = tr16m<128>(a);
                nl1 = tr16m<1024>(a); nh1 = tr16m<1152>(a);
                wait_lgkm<4>();
            } else {
                wait_lgkm<0>();
            }
            __builtin_amdgcn_sched_barrier(0);
            short8 pa0 = cat8(pl0, ph0);
            short8 pa1 = cat8(pl1, ph1);
            oacc[i][0] = mfma16(pa0, vb[0], oacc[i][0]);
            oacc[i][1] = mfma16(pa0, vb[1], oacc[i][1]);
            oacc[i][0] = mfma16(pa1, vb[2], oacc[i][0]);
            oacc[i][1] = mfma16(pa1, vb[3], oacc[i][1]);
            lacc[i] = mfma16(pa0, bones, lacc[i]);
            lacc[i] = mfma16(pa1, bones, lacc[i]);
            if (i < 3) { pl0 = nl0; ph0 = nh0; pl1 = nl1; ph1 = nh1; }
        }

        if (more) {
            int nb = 1 - cur;
            *(short8*)(kdst + nb * 2304) = knx;
            *(short8*)(vdst + nb * 2048) = vnx;
        }
    }

    unsigned short* Op = out + (size_t)head * M_TOK * 32;
    #pragma unroll
    for (int i = 0; i < 4; i++) {
        float inv[4];
        #pragma unroll
        for (int r = 0; r < 4; r++) {
            float sum = __shfl(lacc[i][r], lane & 48);
            inv[r] = 1.f / sum;
        }
        int wy = w * 4 + i;
        #pragma unroll
        for (int dt = 0; dt < 2; dt++)
            #pragma unroll
            for (int r = 0; r < 4; r++) {
                size_t tok = (size_t)(iy * 16 + wy) * HW + ix * 16 + h * 4 + r;
                Op[tok * 32 + dt * 16 + m] = f2bf(oacc[i][dt][r] * inv[r]);
            }
    }
}

extern "C" void kernel_launch(void* const* d_in, const int* in_sizes, int n_in,
                              void* d_out, int out_size, void* d_ws, size_t ws_size,
                              hipStream_t stream) {
    const float* x     = (const float*)d_in[0];
    const int*   rpi   = (const int*)d_in[1];
    const float* n1g   = (const float*)d_in[4];
    const float* n1b   = (const float*)d_in[5];
    const float* qkvw  = (const float*)d_in[6];
    const float* qkvb  = (const float*)d_in[7];
    const float* rpb   = (const float*)d_in[8];
    const float* projw = (const float*)d_in[9];
    const float* projb = (const float*)d_in[10];
    const float* n2g   = (const float*)d_in[11];
    const float* n2b   = (const float*)d_in[12];
    const float* fc1w  = (const float*)d_in[13];
    const float* fc1b  = (const float*)d_in[14];
    const float* fc2w  = (const float*)d_in[15];
    const float* fc2b  = (const float*)d_in[16];

    char* ws = (char*)d_ws;
    unsigned short* wt_qkv  = (unsigned short*)ws;          // 110592 elems
    unsigned short* wt_proj = wt_qkv + 110592;              // 36864
    unsigned short* wt_fc1  = wt_proj + 36864;              // 73728
    unsigned short* wt_fc2  = wt_fc1 + 73728;               // 73728
    unsigned short* btf     = (unsigned short*)(ws + 589824);    // 884736 bf16
    unsigned short* xn      = (unsigned short*)(ws + 4128768);   // 36864*192 bf16
    unsigned short* qkv     = (unsigned short*)(ws + 18284544);  // planar [18][36864][32]
    unsigned short* attn_o  = (unsigned short*)(ws + 60751872);  // planar [6][36864][32]

    prep_kernel<<<9648, 256, 0, stream>>>(qkvw, x, n1g, n1b, wt_qkv, xn);
    qkv_kernel<<<2160, 256, 0, stream>>>(
        xn, wt_qkv, qkvb, qkv,
        rpi, rpb, btf, projw, fc1w, fc2w, wt_proj, wt_fc1, wt_fc2);
    attn_mfma_kernel<<<dim3(144, 6), 256, 0, stream>>>(qkv, btf, attn_o);
    mega_kernel<<<576, 256, 0, stream>>>(
        attn_o, wt_proj, wt_fc1, wt_fc2, projb, fc1b, fc2b,
        x, n2g, n2b, (float*)d_out);
}

// Round 19
// 130.602 us; speedup vs baseline: 1.0433x; 1.0433x over previous
//
#include <hip/hip_runtime.h>
#include <hip/hip_bf16.h>

#define NH 6
#define DIM 192
#define HW 192
#define M_TOK (HW*HW)
// SCALE*log2e and log2e
#define QSC 0.25503488f
#define L2E 1.4426950408889634f

typedef __attribute__((ext_vector_type(8))) __bf16 bf16x8;
typedef __attribute__((ext_vector_type(8))) short short8;
typedef __attribute__((ext_vector_type(4))) short s16x4;
typedef __attribute__((ext_vector_type(4))) float floatx4;

__device__ inline unsigned short f2bf(float f) {
    union { float f; unsigned int u; } v; v.f = f;
    unsigned int r = (v.u + 0x7FFFu + ((v.u >> 16) & 1u)) >> 16;
    return (unsigned short)r;
}
__device__ inline short f2bfh(float f) {
    __bf16 b = (__bf16)f;
    return __builtin_bit_cast(short, b);
}
__device__ inline float exp2fast(float x) {
#if __has_builtin(__builtin_amdgcn_exp2f)
    return __builtin_amdgcn_exp2f(x);
#else
    return exp2f(x);
#endif
}
// bf16x4 -> f32x4 (bit shift)
__device__ inline floatx4 bf4f(s16x4 b) {
    floatx4 f;
    #pragma unroll
    for (int r = 0; r < 4; r++) {
        union { unsigned u; float f; } v;
        v.u = ((unsigned)(unsigned short)b[r]) << 16;
        f[r] = v.f;
    }
    return f;
}

__device__ inline floatx4 mfma16(short8 a, short8 b, floatx4 c) {
    return __builtin_amdgcn_mfma_f32_16x16x32_bf16(
        __builtin_bit_cast(bf16x8, a), __builtin_bit_cast(bf16x8, b), c, 0, 0, 0);
}

template <int OFF>
__device__ inline s16x4 tr16(unsigned addr) {
    s16x4 r;
    asm volatile("ds_read_b64_tr_b16 %0, %1 offset:%2"
                 : "=&v"(r) : "v"(addr), "i"(OFF));
    return r;
}
template <int OFF>
__device__ inline s16x4 tr16m(unsigned addr) {
    s16x4 r;
    asm volatile("ds_read_b64_tr_b16 %0, %1 offset:%2"
                 : "=&v"(r) : "v"(addr), "i"(OFF) : "memory");
    return r;
}
template <int N>
__device__ __forceinline__ void wait_lgkm() {
    asm volatile("s_waitcnt lgkmcnt(%0)" :: "i"(N) : "memory");
}
template <int N>
__device__ __forceinline__ void wait_vm() {
    asm volatile("s_waitcnt vmcnt(%0)" :: "i"(N) : "memory");
}
__device__ __forceinline__ void bar_raw() {
    asm volatile("s_barrier" ::: "memory");
}
__device__ inline short8 cat8(s16x4 a, s16x4 b) {
    return __builtin_shufflevector(a, b, 0, 1, 2, 3, 4, 5, 6, 7);
}

// async global->LDS, 16B per lane; lds_off = wave-uniform LDS byte offset
__device__ __forceinline__ void gload16(const void* g, unsigned lds_off) {
    __builtin_amdgcn_global_load_lds(
        (const __attribute__((address_space(1))) unsigned int*)(uintptr_t)g,
        (__attribute__((address_space(3))) unsigned int*)(uintptr_t)lds_off,
        16, 0, 0);
}

// ---- side-work bodies (shared by prep and gemm<0> extra blocks) ----
__device__ __forceinline__ void btfrag_body(int id, const int* __restrict__ rpi,
                                            const float* __restrict__ table,
                                            unsigned short* __restrict__ btf) {
    int lane = id & 63;
    int t = id >> 6;
    int kt = t % 36; t /= 36;
    int qt = t & 15; int hh = t >> 4;
    int k = kt * 16 + (lane & 15);
    int qb = qt * 16 + (lane >> 4) * 4;
    s16x4 v;
    #pragma unroll
    for (int r = 0; r < 4; r++)
        v[r] = f2bfh(table[rpi[(qb + r) * 576 + k] * NH + hh] * L2E);
    *(s16x4*)&btf[(size_t)id * 4] = v;
}

__device__ __forceinline__ void wcast_rest_body(int i2, const float* __restrict__ projw,
                                                const float* __restrict__ fc1w,
                                                const float* __restrict__ fc2w,
                                                unsigned short* __restrict__ wt_proj,
                                                unsigned short* __restrict__ wt_fc1,
                                                unsigned short* __restrict__ wt_fc2) {
    if (i2 < 36864) {
        int n = i2 / 192, k = i2 - n * 192;
        wt_proj[i2] = f2bf(projw[k * 192 + n]);
    } else if (i2 < 110592) {
        int i = i2 - 36864;
        int n = i / 192, k = i - n * 192;
        wt_fc1[i] = f2bf(fc1w[k * 384 + n]);
    } else {
        int i = i2 - 110592;
        int n = i / 384, k = i - n * 384;
        wt_fc2[i] = f2bf(fc2w[k * 192 + n]);
    }
}

// ---- prep: wcast-qkv + LayerNorm1 only (gates the qkv GEMM) ----
__global__ __launch_bounds__(256) void prep_kernel(
    const float* __restrict__ qkvw,
    const float* __restrict__ x, const float* __restrict__ n1g,
    const float* __restrict__ n1b,
    unsigned short* __restrict__ wt_qkv,
    unsigned short* __restrict__ xn) {
    int bid = blockIdx.x;
    if (bid < 432) {
        int id = bid * 256 + threadIdx.x;   // < 110592
        int n = id / 192, k = id - n * 192;
        wt_qkv[id] = f2bf(qkvw[k * 576 + n]);
    } else {
        int row = (bid - 432) * 4 + (threadIdx.x >> 6);
        int lane = threadIdx.x & 63;
        const float* r = x + (size_t)row * DIM;
        float x0 = r[lane], x1 = r[lane + 64], x2 = r[lane + 128];
        float s = x0 + x1 + x2;
        #pragma unroll
        for (int m = 32; m >= 1; m >>= 1) s += __shfl_xor(s, m);
        float mean = s * (1.f / 192.f);
        float d0 = x0 - mean, d1 = x1 - mean, d2 = x2 - mean;
        float v = d0 * d0 + d1 * d1 + d2 * d2;
        #pragma unroll
        for (int m = 32; m >= 1; m >>= 1) v += __shfl_xor(v, m);
        float rstd = rsqrtf(v * (1.f / 192.f) + 1e-5f);
        unsigned short* o = xn + (size_t)row * DIM;
        o[lane]       = f2bf(d0 * rstd * n1g[lane]       + n1b[lane]);
        o[lane + 64]  = f2bf(d1 * rstd * n1g[lane + 64]  + n1b[lane + 64]);
        o[lane + 128] = f2bf(d2 * rstd * n1g[lane + 128] + n1b[lane + 128]);
    }
}

// ---- bf16 MFMA GEMM (qkv), global_load_lds staging, 96-col K-slabs ----
// Extra blocks (by>=9) do btfrag + wcast of proj/fc1/fc2 weights.
template <int MODE, int KK>
__global__ __launch_bounds__(256, 4) void gemm_kernel(
    const unsigned short* __restrict__ A,
    const unsigned short* __restrict__ Wt,
    const float* __restrict__ bias,
    void* __restrict__ outp,
    int N,
    const int* __restrict__ rpi, const float* __restrict__ table,
    unsigned short* __restrict__ btf,
    const float* __restrict__ projw, const float* __restrict__ fc1w,
    const float* __restrict__ fc2w,
    unsigned short* __restrict__ wt_proj, unsigned short* __restrict__ wt_fc1,
    unsigned short* __restrict__ wt_fc2) {
    if (MODE == 0 && blockIdx.y >= 9) {
        int extra = (blockIdx.y - 9) * 288 + blockIdx.x;
        if (extra < 864) {
            btfrag_body(extra * 256 + threadIdx.x, rpi, table, btf);
        } else if (extra < 1584) {
            wcast_rest_body((extra - 864) * 256 + threadIdx.x,
                            projw, fc1w, fc2w, wt_proj, wt_fc1, wt_fc2);
        }
        return;
    }
    __shared__ __align__(16) short sAB[19968];   // A: 13312 shorts, B at 13312
    constexpr int STAGES = KK / 96;
    int tid = threadIdx.x;
    int w = tid >> 6, lane = tid & 63;
    int bm = blockIdx.x, bn = blockIdx.y;
    int lr = lane & 15, h = lane >> 4;
    floatx4 acc[2][4];
    #pragma unroll
    for (int i = 0; i < 2; i++)
        #pragma unroll
        for (int j = 0; j < 4; j++) acc[i][j] = (floatx4){0.f, 0.f, 0.f, 0.f};

    unsigned ldsbase = (unsigned)(uintptr_t)&sAB[0];

    for (int s = 0; s < STAGES; s++) {
        if (s) __syncthreads();
        for (int W = w; W < 39; W += 4) {
            int o = W * 1024 + lane * 16;
            const unsigned short* src;
            if (o < 26624) {
                int r = o / 208;
                int c = (o - r * 208) >> 4; c = c < 12 ? c : 11;
                src = &A[(size_t)(bm * 128 + r) * KK + s * 96 + c * 8];
            } else {
                int o2 = o - 26624;
                int r = o2 / 208;
                int c = (o2 - r * 208) >> 4; c = c < 12 ? c : 11;
                src = &Wt[(size_t)(bn * 64 + r) * KK + s * 96 + c * 8];
            }
            gload16(src, ldsbase + (unsigned)(W * 1024));
        }
        __syncthreads();
        #pragma unroll
        for (int kk = 0; kk < 3; kk++) {
            int kc = (kk * 4 + h) * 8;
            short8 a0 = *(const short8*)&sAB[(w * 32 + lr) * 104 + kc];
            short8 a1 = *(const short8*)&sAB[(w * 32 + 16 + lr) * 104 + kc];
            short8 b0 = *(const short8*)&sAB[13312 + (lr) * 104 + kc];
            short8 b1 = *(const short8*)&sAB[13312 + (16 + lr) * 104 + kc];
            short8 b2 = *(const short8*)&sAB[13312 + (32 + lr) * 104 + kc];
            short8 b3 = *(const short8*)&sAB[13312 + (48 + lr) * 104 + kc];
            acc[0][0] = mfma16(a0, b0, acc[0][0]);
            acc[0][1] = mfma16(a0, b1, acc[0][1]);
            acc[0][2] = mfma16(a0, b2, acc[0][2]);
            acc[0][3] = mfma16(a0, b3, acc[0][3]);
            acc[1][0] = mfma16(a1, b0, acc[1][0]);
            acc[1][1] = mfma16(a1, b1, acc[1][1]);
            acc[1][2] = mfma16(a1, b2, acc[1][2]);
            acc[1][3] = mfma16(a1, b3, acc[1][3]);
        }
    }

    int rowbase = bm * 128 + w * 32 + h * 4;
    int colbase = bn * 64;
    #pragma unroll
    for (int mi = 0; mi < 2; mi++) {
        #pragma unroll
        for (int ni = 0; ni < 4; ni++) {
            int c = colbase + ni * 16 + lr;
            float bv = bias[c];
            #pragma unroll
            for (int j = 0; j < 4; j++) {
                int r = rowbase + mi * 16 + j;
                float v = acc[mi][ni][j] + bv;
                if (MODE == 0) {
                    int part = c / 192;
                    int rem = c - part * 192;
                    int hd = rem >> 5, d = rem & 31;
                    if (part == 0) v *= QSC;
                    ((unsigned short*)outp)[((size_t)(part * 6 + hd) * M_TOK + r) * 32 + d] = f2bf(v);
                }
            }
        }
    }
}

// ---- MEGA v2: proj + res + LN2 + fc1 + GELU + fc2 + add, reg-prefetched ----
// Block = 64 tokens, 4 waves. x2 in 48 VGPRs. LDS 48KB -> 3 blocks/CU,
// 576 blocks in ONE generation. Weight slabs prefetched to registers one
// stage ahead; raw s_barrier + counted waits (loads never drained at bar).
__global__ __launch_bounds__(256, 3) void mega_kernel(
    const unsigned short* __restrict__ Aop,    // attn_o planar [6][M_TOK][32]
    const unsigned short* __restrict__ Wp,     // wt_proj [192][192]
    const unsigned short* __restrict__ W1,     // wt_fc1  [384][192]
    const unsigned short* __restrict__ W2,     // wt_fc2  [192][384]
    const float* __restrict__ pb,
    const float* __restrict__ b1,
    const float* __restrict__ b2f,
    const float* __restrict__ res,
    const float* __restrict__ g2, const float* __restrict__ bb2,
    float* __restrict__ outp) {
    __shared__ __align__(16) short sA[13312];  // 2 slabs of [64][104] (attn_o -> ln)
    __shared__ __align__(16) short sH[4608];   // [64][72] h quarter
    __shared__ __align__(16) short sB[6656];   // weight slab [64][104] or [64][72]
    int tid = threadIdx.x;
    int w = tid >> 6, lane = tid & 63;
    int bm = blockIdx.x;
    int lr = lane & 15, h = lane >> 4;
    int lrow0 = w * 16 + h * 4;
    int row0 = bm * 64 + lrow0;

    floatx4 x2a[12];
    #pragma unroll
    for (int t = 0; t < 12; t++) x2a[t] = (floatx4){0.f, 0.f, 0.f, 0.f};

    short8 rg0, rg1, rg2;
    auto loadreg96 = [&](const unsigned short* base) {
        #pragma unroll
        for (int k = 0; k < 3; k++) {
            int d = (k * 256 + tid) * 16;
            int r = d / 192, cc = (d - r * 192) >> 1;
            short8 v = *(const short8*)&base[r * 192 + cc];
            if (k == 0) rg0 = v; else if (k == 1) rg1 = v; else rg2 = v;
        }
    };
    auto write96 = [&]() {
        #pragma unroll
        for (int k = 0; k < 3; k++) {
            int d = (k * 256 + tid) * 16;
            int r = d / 192, cc = (d - r * 192) >> 1;
            *(short8*)&sB[r * 104 + cc] = (k == 0) ? rg0 : (k == 1) ? rg1 : rg2;
        }
    };
    auto loadreg64 = [&](const unsigned short* base) {
        #pragma unroll
        for (int k = 0; k < 2; k++) {
            int d = (k * 256 + tid) * 16;
            int r = d / 128, cc = (d - r * 128) >> 1;
            short8 v = *(const short8*)&base[r * 384 + cc];
            if (k == 0) rg0 = v; else rg1 = v;
        }
    };
    auto write64 = [&]() {
        #pragma unroll
        for (int k = 0; k < 2; k++) {
            int d = (k * 256 + tid) * 16;
            int r = d / 128, cc = (d - r * 128) >> 1;
            *(short8*)&sB[r * 72 + cc] = (k == 0) ? rg0 : rg1;
        }
    };

    auto comp96 = [&](floatx4* acc, const short* Ap) {
        #pragma unroll
        for (int kk = 0; kk < 3; kk++) {
            int kc = (kk * 4 + h) * 8;
            short8 a = *(const short8*)&Ap[(w * 16 + lr) * 104 + kc];
            #pragma unroll
            for (int ni = 0; ni < 4; ni++) {
                short8 b = *(const short8*)&sB[(ni * 16 + lr) * 104 + kc];
                acc[ni] = mfma16(a, b, acc[ni]);
            }
        }
    };
    auto comp64 = [&](floatx4* acc) {
        #pragma unroll
        for (int kk = 0; kk < 2; kk++) {
            int kc = (kk * 4 + h) * 8;
            short8 a = *(const short8*)&sH[(w * 16 + lr) * 72 + kc];
            #pragma unroll
            for (int ni = 0; ni < 4; ni++) {
                short8 b = *(const short8*)&sB[(ni * 16 + lr) * 72 + kc];
                acc[ni] = mfma16(a, b, acc[ni]);
            }
        }
    };

#define SCH __builtin_amdgcn_sched_barrier(0)
#define ST96(LOADER, ACC, AP) \
    bar_raw(); wait_vm<0>(); SCH; write96(); LOADER; wait_lgkm<0>(); SCH; \
    bar_raw(); comp96(ACC, AP);
#define ST96F(LOADER, ACC, AP) \
    wait_vm<0>(); SCH; write96(); LOADER; wait_lgkm<0>(); SCH; \
    bar_raw(); comp96(ACC, AP);
#define ST64(LOADER, ACC) \
    bar_raw(); wait_vm<0>(); SCH; write64(); LOADER; wait_lgkm<0>(); SCH; \
    bar_raw(); comp64(ACC);

    {   // stage attn_o tile [64][192] into sA (2 slabs) via gload_lds
        unsigned ldsA = (unsigned)(uintptr_t)&sA[0];
        for (int W = w; W < 26; W += 4) {
            int o = W * 1024 + lane * 16;
            int sl = o / 13312;
            int o2 = o - sl * 13312;
            int r = o2 / 208;
            int c = (o2 - r * 208) >> 4; c = c < 12 ? c : 11;
            int col = sl * 96 + c * 8;
            int hd = col >> 5, d = col & 31;
            gload16(&Aop[((size_t)hd * M_TOK + bm * 64 + r) * 32 + d],
                    ldsA + (unsigned)(W * 1024));
        }
    }
    loadreg96(Wp);                                     // proj ks0 g0

    // ---- proj: 6 stages ----
    ST96F(loadreg96(Wp + 64 * 192),        &x2a[0], sA);          // ks0 g0
    ST96(loadreg96(Wp + 128 * 192),        &x2a[4], sA);          // ks0 g1
    ST96(loadreg96(Wp + 96),               &x2a[8], sA);          // ks0 g2
    ST96(loadreg96(Wp + 64 * 192 + 96),    &x2a[0], sA + 6656);   // ks1 g0
    ST96(loadreg96(Wp + 128 * 192 + 96),   &x2a[4], sA + 6656);   // ks1 g1
    ST96(loadreg96(W1),                    &x2a[8], sA + 6656);   // ks1 g2

    // ---- proj epilogue: x2 = acc + pb + res; LN2 -> sA (own rows) ----
    {
        float s1[4] = {0.f, 0.f, 0.f, 0.f}, s2[4] = {0.f, 0.f, 0.f, 0.f};
        #pragma unroll
        for (int t = 0; t < 12; t++) {
            int c = t * 16 + lr;
            float bv = pb[c];
            #pragma unroll
            for (int j = 0; j < 4; j++) {
                size_t idx = (size_t)(row0 + j) * 192 + c;
                float v = x2a[t][j] + bv + res[idx];
                x2a[t][j] = v;
                s1[j] += v;
                s2[j] += v * v;
            }
        }
        #pragma unroll
        for (int mask = 1; mask <= 8; mask <<= 1) {
            #pragma unroll
            for (int j = 0; j < 4; j++) {
                s1[j] += __shfl_xor(s1[j], mask);
                s2[j] += __shfl_xor(s2[j], mask);
            }
        }
        float mean[4], rstd[4];
        #pragma unroll
        for (int j = 0; j < 4; j++) {
            mean[j] = s1[j] * (1.f / 192.f);
            float var = s2[j] * (1.f / 192.f) - mean[j] * mean[j];
            rstd[j] = rsqrtf(var + 1e-5f);
        }
        #pragma unroll
        for (int t = 0; t < 12; t++) {
            int c = t * 16 + lr;
            float gw = g2[c], bw = bb2[c];
            int slab = t / 6;
            int cc = c - slab * 96;
            #pragma unroll
            for (int j = 0; j < 4; j++) {
                float lnv = (x2a[t][j] - mean[j]) * rstd[j] * gw + bw;
                sA[slab * 6656 + (lrow0 + j) * 104 + cc] = f2bfh(lnv);
            }
        }
    }

    // ---- MLP: per 64-col h-group: fc1 ks0, fc1 ks1, gelu, fc2 g0..g2 ----
    for (int hg = 0; hg < 6; hg++) {
        floatx4 ha[4];
        #pragma unroll
        for (int ni = 0; ni < 4; ni++) ha[ni] = (floatx4){0.f, 0.f, 0.f, 0.f};

        ST96(loadreg96(W1 + (size_t)(hg * 64) * 192 + 96), ha, sA);         // fc1 ks0
        ST96(loadreg64(W2 + hg * 64),                      ha, sA + 6656);  // fc1 ks1

        // gelu + bias -> sH (own rows)
        #pragma unroll
        for (int ni = 0; ni < 4; ni++) {
            int hc = hg * 64 + ni * 16 + lr;
            float bv = b1[hc];
            #pragma unroll
            for (int j = 0; j < 4; j++) {
                float v = ha[ni][j] + bv;
                float gl = 0.5f * v * (1.f + erff(v * 0.70710678118654752f));
                sH[(lrow0 + j) * 72 + ni * 16 + lr] = f2bfh(gl);
            }
        }

        ST64(loadreg64(W2 + (size_t)64 * 384 + hg * 64),  &x2a[0]);   // fc2 g0
        ST64(loadreg64(W2 + (size_t)128 * 384 + hg * 64), &x2a[4]);   // fc2 g1
        if (hg < 5) {
            ST64(loadreg96(W1 + (size_t)((hg + 1) * 64) * 192), &x2a[8]);
        } else {
            ST64(, &x2a[8]);
        }
    }
#undef ST96
#undef ST96F
#undef ST64
#undef SCH

    // ---- final: out = x2 + mlp + fc2b ----
    #pragma unroll
    for (int t = 0; t < 12; t++) {
        int c = t * 16 + lr;
        float bv = b2f[c];
        #pragma unroll
        for (int j = 0; j < 4; j++) {
            size_t idx = (size_t)(row0 + j) * 192 + c;
            outp[idx] = x2a[t][j] + bv;
        }
    }
}

// ---- MFMA windowed attention: r11-exact two-phase structure, planar QKV ----
__global__ __launch_bounds__(256, 3) void attn_mfma_kernel(
    const unsigned short* __restrict__ qkv,
    const unsigned short* __restrict__ btf,
    unsigned short* __restrict__ out) {
    __shared__ __align__(16) short sK[2][2304];
    __shared__ __align__(16) short sV[2][2048];
    __shared__ __align__(16) short sPt[4][4096];
    int win = blockIdx.x, head = blockIdx.y;
    int iy = win / 12, ix = win % 12;
    int tid = threadIdx.x;
    int w = tid >> 6, lane = tid & 63;
    int m = lane & 15, h = lane >> 4;

    const unsigned short* Qp = qkv + (size_t)head * M_TOK * 32;
    const unsigned short* Kp = qkv + (size_t)(6 + head) * M_TOK * 32;

    short8 qf[4];
    #pragma unroll
    for (int i = 0; i < 4; i++) {
        int wy = w * 4 + i;
        size_t tok = (size_t)(iy * 16 + wy) * HW + ix * 16 + m;
        qf[i] = *(const short8*)&Qp[tok * 32 + h * 8];
    }

    short ob = (m == 0) ? (short)0x3F80 : (short)0;
    short8 bones = {ob, ob, ob, ob, ob, ob, ob, ob};

    floatx4 oacc[4][2];
    floatx4 lacc[4];
    #pragma unroll
    for (int i = 0; i < 4; i++) {
        lacc[i] = (floatx4){0.f, 0.f, 0.f, 0.f};
        oacc[i][0] = (floatx4){0.f, 0.f, 0.f, 0.f};
        oacc[i][1] = (floatx4){0.f, 0.f, 0.f, 0.f};
    }

    int skey = tid >> 2, dq = tid & 3;
    short* kdst = &sK[0][skey * 36 + dq * 8];
    short* vdst = &sV[0][(dq >> 1) * 1024 + (skey >> 2) * 64 + (skey & 3) * 16 + (dq & 1) * 8];

    auto fetch = [&](int c, short8& kv, short8& vv) {
        int key = c * 64 + skey;
        int oy = key / 24, ox = key - (key / 24) * 24;
        int gy = iy * 16 - 4 + oy, gx = ix * 16 - 4 + ox;
        kv = (short8){0,0,0,0,0,0,0,0};
        vv = (short8){0,0,0,0,0,0,0,0};
        if (gy >= 0 && gy < HW && gx >= 0 && gx < HW) {
            const unsigned short* p = &Kp[((size_t)gy * HW + gx) * 32 + dq * 8];
            kv = *(const short8*)p;
            vv = *(const short8*)(p + 6 * M_TOK * 32);
        }
    };

    {   // stage chunk 0 into buffer 0
        short8 kv, vv;
        fetch(0, kv, vv);
        *(short8*)kdst = kv;
        *(short8*)vdst = vv;
    }

    unsigned sPbase = (unsigned)(uintptr_t)&sPt[w][0];
    unsigned sPa = sPbase + 8 * m + 256 * h;
    unsigned sVa0 = (unsigned)(uintptr_t)&sV[0][0] + 8 * m + 256 * h;
    char* sPwb = (char*)&sPt[w][0] + 128 * (m >> 2) + 32 * (m & 3) + 8 * h;

    for (int c = 0; c < 9; c++) {
        __syncthreads();
        int cur = c & 1;
        short8 knx, vnx;
        bool more = (c < 8);
        if (more) fetch(c + 1, knx, vnx);

        const short* sKc = sK[cur];
        short8 kfrag[4];
        #pragma unroll
        for (int kt = 0; kt < 4; kt++)
            kfrag[kt] = *(const short8*)&sKc[(kt * 16 + m) * 36 + h * 8];

        const unsigned short* bb = btf + ((((size_t)head * 16 + w * 4) * 36 + c * 4) * 64 + lane) * 4;

        #pragma unroll
        for (int i = 0; i < 4; i++) {
            floatx4 s[4];
            #pragma unroll
            for (int kt = 0; kt < 4; kt++)
                s[kt] = bf4f(*(const s16x4*)&bb[(size_t)(i * 36 + kt) * 256]);
            #pragma unroll
            for (int kt = 0; kt < 4; kt++)
                s[kt] = mfma16(qf[i], kfrag[kt], s[kt]);
            #pragma unroll
            for (int kt = 0; kt < 4; kt++) {
                s16x4 pk;
                #pragma unroll
                for (int r = 0; r < 4; r++)
                    pk[r] = f2bfh(exp2fast(s[kt][r]));
                *(s16x4*)(sPwb + i * 2048 + kt * 512) = pk;
            }
        }

        unsigned sVa = sVa0 + cur * 4096;
        short8 vb[4];
        {
            s16x4 lo0 = tr16<0>(sVa),    hi0 = tr16<128>(sVa);
            s16x4 lo1 = tr16<2048>(sVa), hi1 = tr16<2176>(sVa);
            s16x4 lo2 = tr16<1024>(sVa), hi2 = tr16<1152>(sVa);
            s16x4 lo3 = tr16<3072>(sVa), hi3 = tr16<3200>(sVa);
            vb[0] = cat8(lo0, hi0);
            vb[1] = cat8(lo1, hi1);
            vb[2] = cat8(lo2, hi2);
            vb[3] = cat8(lo3, hi3);
        }
        s16x4 pl0 = tr16m<0>(sPa),    ph0 = tr16m<128>(sPa);
        s16x4 pl1 = tr16m<1024>(sPa), ph1 = tr16m<1152>(sPa);
        #pragma unroll
        for (int i = 0; i < 4; i++) {
            s16x4 nl0, nh0, nl1, nh1;
            if (i < 3) {
                unsigned a = sPa + (unsigned)((i + 1) * 2048);
                nl0 = tr16m<0>(a);    nh0 = tr16m<128>(a);
                nl1 = tr16m<1024>(a); nh1 = tr16m<1152>(a);
                wait_lgkm<4>();
            } else {
                wait_lgkm<0>();
            }
            __builtin_amdgcn_sched_barrier(0);
            short8 pa0 = cat8(pl0, ph0);
            short8 pa1 = cat8(pl1, ph1);
            oacc[i][0] = mfma16(pa0, vb[0], oacc[i][0]);
            oacc[i][1] = mfma16(pa0, vb[1], oacc[i][1]);
            oacc[i][0] = mfma16(pa1, vb[2], oacc[i][0]);
            oacc[i][1] = mfma16(pa1, vb[3], oacc[i][1]);
            lacc[i] = mfma16(pa0, bones, lacc[i]);
            lacc[i] = mfma16(pa1, bones, lacc[i]);
            if (i < 3) { pl0 = nl0; ph0 = nh0; pl1 = nl1; ph1 = nh1; }
        }

        if (more) {
            int nb = 1 - cur;
            *(short8*)(kdst + nb * 2304) = knx;
            *(short8*)(vdst + nb * 2048) = vnx;
        }
    }

    unsigned short* Op = out + (size_t)head * M_TOK * 32;
    #pragma unroll
    for (int i = 0; i < 4; i++) {
        float inv[4];
        #pragma unroll
        for (int r = 0; r < 4; r++) {
            float sum = __shfl(lacc[i][r], lane & 48);
            inv[r] = 1.f / sum;
        }
        int wy = w * 4 + i;
        #pragma unroll
        for (int dt = 0; dt < 2; dt++)
            #pragma unroll
            for (int r = 0; r < 4; r++) {
                size_t tok = (size_t)(iy * 16 + wy) * HW + ix * 16 + h * 4 + r;
                Op[tok * 32 + dt * 16 + m] = f2bf(oacc[i][dt][r] * inv[r]);
            }
    }
}

extern "C" void kernel_launch(void* const* d_in, const int* in_sizes, int n_in,
                              void* d_out, int out_size, void* d_ws, size_t ws_size,
                              hipStream_t stream) {
    const float* x     = (const float*)d_in[0];
    const int*   rpi   = (const int*)d_in[1];
    const float* n1g   = (const float*)d_in[4];
    const float* n1b   = (const float*)d_in[5];
    const float* qkvw  = (const float*)d_in[6];
    const float* qkvb  = (const float*)d_in[7];
    const float* rpb   = (const float*)d_in[8];
    const float* projw = (const float*)d_in[9];
    const float* projb = (const float*)d_in[10];
    const float* n2g   = (const float*)d_in[11];
    const float* n2b   = (const float*)d_in[12];
    const float* fc1w  = (const float*)d_in[13];
    const float* fc1b  = (const float*)d_in[14];
    const float* fc2w  = (const float*)d_in[15];
    const float* fc2b  = (const float*)d_in[16];

    char* ws = (char*)d_ws;
    unsigned short* wt_qkv  = (unsigned short*)ws;          // 110592 elems
    unsigned short* wt_proj = wt_qkv + 110592;              // 36864
    unsigned short* wt_fc1  = wt_proj + 36864;              // 73728
    unsigned short* wt_fc2  = wt_fc1 + 73728;               // 73728
    unsigned short* btf     = (unsigned short*)(ws + 589824);    // 884736 bf16
    unsigned short* xn      = (unsigned short*)(ws + 4128768);   // 36864*192 bf16
    unsigned short* qkv     = (unsigned short*)(ws + 18284544);  // planar [18][36864][32]
    unsigned short* attn_o  = (unsigned short*)(ws + 60751872);  // planar [6][36864][32]

    prep_kernel<<<9648, 256, 0, stream>>>(qkvw, x, n1g, n1b, wt_qkv, xn);
    gemm_kernel<0, 192><<<dim3(288, 15), 256, 0, stream>>>(
        xn, wt_qkv, qkvb, qkv, 576,
        rpi, rpb, btf, projw, fc1w, fc2w, wt_proj, wt_fc1, wt_fc2);
    attn_mfma_kernel<<<dim3(144, 6), 256, 0, stream>>>(qkv, btf, attn_o);
    mega_kernel<<<576, 256, 0, stream>>>(
        attn_o, wt_proj, wt_fc1, wt_fc2, projb, fc1b, fc2b,
        x, n2g, n2b, (float*)d_out);
}

// Round 20
// 129.614 us; speedup vs baseline: 1.0512x; 1.0076x over previous
//
#include <hip/hip_runtime.h>
#include <hip/hip_bf16.h>

#define NH 6
#define DIM 192
#define HW 192
#define M_TOK (HW*HW)
// SCALE*log2e and log2e
#define QSC 0.25503488f
#define L2E 1.4426950408889634f

typedef __attribute__((ext_vector_type(8))) __bf16 bf16x8;
typedef __attribute__((ext_vector_type(8))) short short8;
typedef __attribute__((ext_vector_type(4))) short s16x4;
typedef __attribute__((ext_vector_type(4))) float floatx4;

__device__ inline unsigned short f2bf(float f) {
    union { float f; unsigned int u; } v; v.f = f;
    unsigned int r = (v.u + 0x7FFFu + ((v.u >> 16) & 1u)) >> 16;
    return (unsigned short)r;
}
__device__ inline short f2bfh(float f) {
    __bf16 b = (__bf16)f;
    return __builtin_bit_cast(short, b);
}
__device__ inline float exp2fast(float x) {
#if __has_builtin(__builtin_amdgcn_exp2f)
    return __builtin_amdgcn_exp2f(x);
#else
    return exp2f(x);
#endif
}
// bf16x4 -> f32x4 (bit shift)
__device__ inline floatx4 bf4f(s16x4 b) {
    floatx4 f;
    #pragma unroll
    for (int r = 0; r < 4; r++) {
        union { unsigned u; float f; } v;
        v.u = ((unsigned)(unsigned short)b[r]) << 16;
        f[r] = v.f;
    }
    return f;
}

__device__ inline floatx4 mfma16(short8 a, short8 b, floatx4 c) {
    return __builtin_amdgcn_mfma_f32_16x16x32_bf16(
        __builtin_bit_cast(bf16x8, a), __builtin_bit_cast(bf16x8, b), c, 0, 0, 0);
}

template <int OFF>
__device__ inline s16x4 tr16(unsigned addr) {
    s16x4 r;
    asm volatile("ds_read_b64_tr_b16 %0, %1 offset:%2"
                 : "=&v"(r) : "v"(addr), "i"(OFF));
    return r;
}
template <int OFF>
__device__ inline s16x4 tr16m(unsigned addr) {
    s16x4 r;
    asm volatile("ds_read_b64_tr_b16 %0, %1 offset:%2"
                 : "=&v"(r) : "v"(addr), "i"(OFF) : "memory");
    return r;
}
template <int N>
__device__ __forceinline__ void wait_lgkm() {
    asm volatile("s_waitcnt lgkmcnt(%0)" :: "i"(N) : "memory");
}
template <int N>
__device__ __forceinline__ void wait_vm() {
    asm volatile("s_waitcnt vmcnt(%0)" :: "i"(N) : "memory");
}
__device__ __forceinline__ void bar_raw() {
    asm volatile("s_barrier" ::: "memory");
}
__device__ inline short8 cat8(s16x4 a, s16x4 b) {
    return __builtin_shufflevector(a, b, 0, 1, 2, 3, 4, 5, 6, 7);
}

// async global->LDS, 16B per lane; lds_off = wave-uniform LDS byte offset
__device__ __forceinline__ void gload16(const void* g, unsigned lds_off) {
    __builtin_amdgcn_global_load_lds(
        (const __attribute__((address_space(1))) unsigned int*)(uintptr_t)g,
        (__attribute__((address_space(3))) unsigned int*)(uintptr_t)lds_off,
        16, 0, 0);
}

// ---- side-work bodies (shared by prep and gemm<0> extra blocks) ----
__device__ __forceinline__ void btfrag_body(int id, const int* __restrict__ rpi,
                                            const float* __restrict__ table,
                                            unsigned short* __restrict__ btf) {
    int lane = id & 63;
    int t = id >> 6;
    int kt = t % 36; t /= 36;
    int qt = t & 15; int hh = t >> 4;
    int k = kt * 16 + (lane & 15);
    int qb = qt * 16 + (lane >> 4) * 4;
    s16x4 v;
    #pragma unroll
    for (int r = 0; r < 4; r++)
        v[r] = f2bfh(table[rpi[(qb + r) * 576 + k] * NH + hh] * L2E);
    *(s16x4*)&btf[(size_t)id * 4] = v;
}

__device__ __forceinline__ void wcast_rest_body(int i2, const float* __restrict__ projw,
                                                const float* __restrict__ fc1w,
                                                const float* __restrict__ fc2w,
                                                unsigned short* __restrict__ wt_proj,
                                                unsigned short* __restrict__ wt_fc1,
                                                unsigned short* __restrict__ wt_fc2) {
    if (i2 < 36864) {
        int n = i2 / 192, k = i2 - n * 192;
        wt_proj[i2] = f2bf(projw[k * 192 + n]);
    } else if (i2 < 110592) {
        int i = i2 - 36864;
        int n = i / 192, k = i - n * 192;
        wt_fc1[i] = f2bf(fc1w[k * 384 + n]);
    } else {
        int i = i2 - 110592;
        int n = i / 384, k = i - n * 384;
        wt_fc2[i] = f2bf(fc2w[k * 192 + n]);
    }
}

// ---- prep: wcast-qkv + LayerNorm1 only (gates the qkv GEMM) ----
__global__ __launch_bounds__(256) void prep_kernel(
    const float* __restrict__ qkvw,
    const float* __restrict__ x, const float* __restrict__ n1g,
    const float* __restrict__ n1b,
    unsigned short* __restrict__ wt_qkv,
    unsigned short* __restrict__ xn) {
    int bid = blockIdx.x;
    if (bid < 432) {
        int id = bid * 256 + threadIdx.x;   // < 110592
        int n = id / 192, k = id - n * 192;
        wt_qkv[id] = f2bf(qkvw[k * 576 + n]);
    } else {
        int row = (bid - 432) * 4 + (threadIdx.x >> 6);
        int lane = threadIdx.x & 63;
        const float* r = x + (size_t)row * DIM;
        float x0 = r[lane], x1 = r[lane + 64], x2 = r[lane + 128];
        float s = x0 + x1 + x2;
        #pragma unroll
        for (int m = 32; m >= 1; m >>= 1) s += __shfl_xor(s, m);
        float mean = s * (1.f / 192.f);
        float d0 = x0 - mean, d1 = x1 - mean, d2 = x2 - mean;
        float v = d0 * d0 + d1 * d1 + d2 * d2;
        #pragma unroll
        for (int m = 32; m >= 1; m >>= 1) v += __shfl_xor(v, m);
        float rstd = rsqrtf(v * (1.f / 192.f) + 1e-5f);
        unsigned short* o = xn + (size_t)row * DIM;
        o[lane]       = f2bf(d0 * rstd * n1g[lane]       + n1b[lane]);
        o[lane + 64]  = f2bf(d1 * rstd * n1g[lane + 64]  + n1b[lane + 64]);
        o[lane + 128] = f2bf(d2 * rstd * n1g[lane + 128] + n1b[lane + 128]);
    }
}

// ---- bf16 MFMA GEMM (qkv), global_load_lds staging, 96-col K-slabs ----
// Extra blocks (by>=9) do btfrag + wcast of proj/fc1/fc2 weights.
template <int MODE, int KK>
__global__ __launch_bounds__(256, 4) void gemm_kernel(
    const unsigned short* __restrict__ A,
    const unsigned short* __restrict__ Wt,
    const float* __restrict__ bias,
    void* __restrict__ outp,
    int N,
    const int* __restrict__ rpi, const float* __restrict__ table,
    unsigned short* __restrict__ btf,
    const float* __restrict__ projw, const float* __restrict__ fc1w,
    const float* __restrict__ fc2w,
    unsigned short* __restrict__ wt_proj, unsigned short* __restrict__ wt_fc1,
    unsigned short* __restrict__ wt_fc2) {
    if (MODE == 0 && blockIdx.y >= 9) {
        int extra = (blockIdx.y - 9) * 288 + blockIdx.x;
        if (extra < 864) {
            btfrag_body(extra * 256 + threadIdx.x, rpi, table, btf);
        } else if (extra < 1584) {
            wcast_rest_body((extra - 864) * 256 + threadIdx.x,
                            projw, fc1w, fc2w, wt_proj, wt_fc1, wt_fc2);
        }
        return;
    }
    __shared__ __align__(16) short sAB[19968];   // A: 13312 shorts, B at 13312
    constexpr int STAGES = KK / 96;
    int tid = threadIdx.x;
    int w = tid >> 6, lane = tid & 63;
    int bm = blockIdx.x, bn = blockIdx.y;
    int lr = lane & 15, h = lane >> 4;
    floatx4 acc[2][4];
    #pragma unroll
    for (int i = 0; i < 2; i++)
        #pragma unroll
        for (int j = 0; j < 4; j++) acc[i][j] = (floatx4){0.f, 0.f, 0.f, 0.f};

    unsigned ldsbase = (unsigned)(uintptr_t)&sAB[0];

    for (int s = 0; s < STAGES; s++) {
        if (s) __syncthreads();
        for (int W = w; W < 39; W += 4) {
            int o = W * 1024 + lane * 16;
            const unsigned short* src;
            if (o < 26624) {
                int r = o / 208;
                int c = (o - r * 208) >> 4; c = c < 12 ? c : 11;
                src = &A[(size_t)(bm * 128 + r) * KK + s * 96 + c * 8];
            } else {
                int o2 = o - 26624;
                int r = o2 / 208;
                int c = (o2 - r * 208) >> 4; c = c < 12 ? c : 11;
                src = &Wt[(size_t)(bn * 64 + r) * KK + s * 96 + c * 8];
            }
            gload16(src, ldsbase + (unsigned)(W * 1024));
        }
        __syncthreads();
        #pragma unroll
        for (int kk = 0; kk < 3; kk++) {
            int kc = (kk * 4 + h) * 8;
            short8 a0 = *(const short8*)&sAB[(w * 32 + lr) * 104 + kc];
            short8 a1 = *(const short8*)&sAB[(w * 32 + 16 + lr) * 104 + kc];
            short8 b0 = *(const short8*)&sAB[13312 + (lr) * 104 + kc];
            short8 b1 = *(const short8*)&sAB[13312 + (16 + lr) * 104 + kc];
            short8 b2 = *(const short8*)&sAB[13312 + (32 + lr) * 104 + kc];
            short8 b3 = *(const short8*)&sAB[13312 + (48 + lr) * 104 + kc];
            acc[0][0] = mfma16(a0, b0, acc[0][0]);
            acc[0][1] = mfma16(a0, b1, acc[0][1]);
            acc[0][2] = mfma16(a0, b2, acc[0][2]);
            acc[0][3] = mfma16(a0, b3, acc[0][3]);
            acc[1][0] = mfma16(a1, b0, acc[1][0]);
            acc[1][1] = mfma16(a1, b1, acc[1][1]);
            acc[1][2] = mfma16(a1, b2, acc[1][2]);
            acc[1][3] = mfma16(a1, b3, acc[1][3]);
        }
    }

    int rowbase = bm * 128 + w * 32 + h * 4;
    int colbase = bn * 64;
    #pragma unroll
    for (int mi = 0; mi < 2; mi++) {
        #pragma unroll
        for (int ni = 0; ni < 4; ni++) {
            int c = colbase + ni * 16 + lr;
            float bv = bias[c];
            #pragma unroll
            for (int j = 0; j < 4; j++) {
                int r = rowbase + mi * 16 + j;
                float v = acc[mi][ni][j] + bv;
                if (MODE == 0) {
                    int part = c / 192;
                    int rem = c - part * 192;
                    int hd = rem >> 5, d = rem & 31;
                    if (part == 0) v *= QSC;
                    ((unsigned short*)outp)[((size_t)(part * 6 + hd) * M_TOK + r) * 32 + d] = f2bf(v);
                }
            }
        }
    }
}

// ---- MEGA v2: proj + res + LN2 + fc1 + GELU + fc2 + add, reg-prefetched ----
__global__ __launch_bounds__(256, 3) void mega_kernel(
    const unsigned short* __restrict__ Aop,    // attn_o planar [6][M_TOK][32]
    const unsigned short* __restrict__ Wp,     // wt_proj [192][192]
    const unsigned short* __restrict__ W1,     // wt_fc1  [384][192]
    const unsigned short* __restrict__ W2,     // wt_fc2  [192][384]
    const float* __restrict__ pb,
    const float* __restrict__ b1,
    const float* __restrict__ b2f,
    const float* __restrict__ res,
    const float* __restrict__ g2, const float* __restrict__ bb2,
    float* __restrict__ outp) {
    __shared__ __align__(16) short sA[13312];  // 2 slabs of [64][104] (attn_o -> ln)
    __shared__ __align__(16) short sH[4608];   // [64][72] h quarter
    __shared__ __align__(16) short sB[6656];   // weight slab [64][104] or [64][72]
    int tid = threadIdx.x;
    int w = tid >> 6, lane = tid & 63;
    int bm = blockIdx.x;
    int lr = lane & 15, h = lane >> 4;
    int lrow0 = w * 16 + h * 4;
    int row0 = bm * 64 + lrow0;

    floatx4 x2a[12];
    #pragma unroll
    for (int t = 0; t < 12; t++) x2a[t] = (floatx4){0.f, 0.f, 0.f, 0.f};

    short8 rg0, rg1, rg2;
    auto loadreg96 = [&](const unsigned short* base) {
        #pragma unroll
        for (int k = 0; k < 3; k++) {
            int d = (k * 256 + tid) * 16;
            int r = d / 192, cc = (d - r * 192) >> 1;
            short8 v = *(const short8*)&base[r * 192 + cc];
            if (k == 0) rg0 = v; else if (k == 1) rg1 = v; else rg2 = v;
        }
    };
    auto write96 = [&]() {
        #pragma unroll
        for (int k = 0; k < 3; k++) {
            int d = (k * 256 + tid) * 16;
            int r = d / 192, cc = (d - r * 192) >> 1;
            *(short8*)&sB[r * 104 + cc] = (k == 0) ? rg0 : (k == 1) ? rg1 : rg2;
        }
    };
    auto loadreg64 = [&](const unsigned short* base) {
        #pragma unroll
        for (int k = 0; k < 2; k++) {
            int d = (k * 256 + tid) * 16;
            int r = d / 128, cc = (d - r * 128) >> 1;
            short8 v = *(const short8*)&base[r * 384 + cc];
            if (k == 0) rg0 = v; else rg1 = v;
        }
    };
    auto write64 = [&]() {
        #pragma unroll
        for (int k = 0; k < 2; k++) {
            int d = (k * 256 + tid) * 16;
            int r = d / 128, cc = (d - r * 128) >> 1;
            *(short8*)&sB[r * 72 + cc] = (k == 0) ? rg0 : rg1;
        }
    };

    auto comp96 = [&](floatx4* acc, const short* Ap) {
        #pragma unroll
        for (int kk = 0; kk < 3; kk++) {
            int kc = (kk * 4 + h) * 8;
            short8 a = *(const short8*)&Ap[(w * 16 + lr) * 104 + kc];
            #pragma unroll
            for (int ni = 0; ni < 4; ni++) {
                short8 b = *(const short8*)&sB[(ni * 16 + lr) * 104 + kc];
                acc[ni] = mfma16(a, b, acc[ni]);
            }
        }
    };
    auto comp64 = [&](floatx4* acc) {
        #pragma unroll
        for (int kk = 0; kk < 2; kk++) {
            int kc = (kk * 4 + h) * 8;
            short8 a = *(const short8*)&sH[(w * 16 + lr) * 72 + kc];
            #pragma unroll
            for (int ni = 0; ni < 4; ni++) {
                short8 b = *(const short8*)&sB[(ni * 16 + lr) * 72 + kc];
                acc[ni] = mfma16(a, b, acc[ni]);
            }
        }
    };

#define SCH __builtin_amdgcn_sched_barrier(0)
#define ST96(LOADER, ACC, AP) \
    bar_raw(); wait_vm<0>(); SCH; write96(); LOADER; wait_lgkm<0>(); SCH; \
    bar_raw(); comp96(ACC, AP);
#define ST96F(LOADER, ACC, AP) \
    wait_vm<0>(); SCH; write96(); LOADER; wait_lgkm<0>(); SCH; \
    bar_raw(); comp96(ACC, AP);
#define ST64(LOADER, ACC) \
    bar_raw(); wait_vm<0>(); SCH; write64(); LOADER; wait_lgkm<0>(); SCH; \
    bar_raw(); comp64(ACC);

    {   // stage attn_o tile [64][192] into sA (2 slabs) via gload_lds
        unsigned ldsA = (unsigned)(uintptr_t)&sA[0];
        for (int W = w; W < 26; W += 4) {
            int o = W * 1024 + lane * 16;
            int sl = o / 13312;
            int o2 = o - sl * 13312;
            int r = o2 / 208;
            int c = (o2 - r * 208) >> 4; c = c < 12 ? c : 11;
            int col = sl * 96 + c * 8;
            int hd = col >> 5, d = col & 31;
            gload16(&Aop[((size_t)hd * M_TOK + bm * 64 + r) * 32 + d],
                    ldsA + (unsigned)(W * 1024));
        }
    }
    loadreg96(Wp);                                     // proj ks0 g0

    // ---- proj: 6 stages ----
    ST96F(loadreg96(Wp + 64 * 192),        &x2a[0], sA);          // ks0 g0
    ST96(loadreg96(Wp + 128 * 192),        &x2a[4], sA);          // ks0 g1
    ST96(loadreg96(Wp + 96),               &x2a[8], sA);          // ks0 g2
    ST96(loadreg96(Wp + 64 * 192 + 96),    &x2a[0], sA + 6656);   // ks1 g0
    ST96(loadreg96(Wp + 128 * 192 + 96),   &x2a[4], sA + 6656);   // ks1 g1
    ST96(loadreg96(W1),                    &x2a[8], sA + 6656);   // ks1 g2

    // ---- proj epilogue: x2 = acc + pb + res; LN2 -> sA (own rows) ----
    {
        float s1[4] = {0.f, 0.f, 0.f, 0.f}, s2[4] = {0.f, 0.f, 0.f, 0.f};
        #pragma unroll
        for (int t = 0; t < 12; t++) {
            int c = t * 16 + lr;
            float bv = pb[c];
            #pragma unroll
            for (int j = 0; j < 4; j++) {
                size_t idx = (size_t)(row0 + j) * 192 + c;
                float v = x2a[t][j] + bv + res[idx];
                x2a[t][j] = v;
                s1[j] += v;
                s2[j] += v * v;
            }
        }
        #pragma unroll
        for (int mask = 1; mask <= 8; mask <<= 1) {
            #pragma unroll
            for (int j = 0; j < 4; j++) {
                s1[j] += __shfl_xor(s1[j], mask);
                s2[j] += __shfl_xor(s2[j], mask);
            }
        }
        float mean[4], rstd[4];
        #pragma unroll
        for (int j = 0; j < 4; j++) {
            mean[j] = s1[j] * (1.f / 192.f);
            float var = s2[j] * (1.f / 192.f) - mean[j] * mean[j];
            rstd[j] = rsqrtf(var + 1e-5f);
        }
        #pragma unroll
        for (int t = 0; t < 12; t++) {
            int c = t * 16 + lr;
            float gw = g2[c], bw = bb2[c];
            int slab = t / 6;
            int cc = c - slab * 96;
            #pragma unroll
            for (int j = 0; j < 4; j++) {
                float lnv = (x2a[t][j] - mean[j]) * rstd[j] * gw + bw;
                sA[slab * 6656 + (lrow0 + j) * 104 + cc] = f2bfh(lnv);
            }
        }
    }

    // ---- MLP: per 64-col h-group: fc1 ks0, fc1 ks1, gelu, fc2 g0..g2 ----
    for (int hg = 0; hg < 6; hg++) {
        floatx4 ha[4];
        #pragma unroll
        for (int ni = 0; ni < 4; ni++) ha[ni] = (floatx4){0.f, 0.f, 0.f, 0.f};

        ST96(loadreg96(W1 + (size_t)(hg * 64) * 192 + 96), ha, sA);         // fc1 ks0
        ST96(loadreg64(W2 + hg * 64),                      ha, sA + 6656);  // fc1 ks1

        // gelu + bias -> sH (own rows)
        #pragma unroll
        for (int ni = 0; ni < 4; ni++) {
            int hc = hg * 64 + ni * 16 + lr;
            float bv = b1[hc];
            #pragma unroll
            for (int j = 0; j < 4; j++) {
                float v = ha[ni][j] + bv;
                float gl = 0.5f * v * (1.f + erff(v * 0.70710678118654752f));
                sH[(lrow0 + j) * 72 + ni * 16 + lr] = f2bfh(gl);
            }
        }

        ST64(loadreg64(W2 + (size_t)64 * 384 + hg * 64),  &x2a[0]);   // fc2 g0
        ST64(loadreg64(W2 + (size_t)128 * 384 + hg * 64), &x2a[4]);   // fc2 g1
        if (hg < 5) {
            ST64(loadreg96(W1 + (size_t)((hg + 1) * 64) * 192), &x2a[8]);
        } else {
            ST64(, &x2a[8]);
        }
    }
#undef ST96
#undef ST96F
#undef ST64
#undef SCH

    // ---- final: out = x2 + mlp + fc2b ----
    #pragma unroll
    for (int t = 0; t < 12; t++) {
        int c = t * 16 + lr;
        float bv = b2f[c];
        #pragma unroll
        for (int j = 0; j < 4; j++) {
            size_t idx = (size_t)(row0 + j) * 192 + c;
            outp[idx] = x2a[t][j] + bv;
        }
    }
}

// ---- MFMA windowed attention: r11 two-phase structure + T5 setprio ----
__global__ __launch_bounds__(256, 3) void attn_mfma_kernel(
    const unsigned short* __restrict__ qkv,
    const unsigned short* __restrict__ btf,
    unsigned short* __restrict__ out) {
    __shared__ __align__(16) short sK[2][2304];
    __shared__ __align__(16) short sV[2][2048];
    __shared__ __align__(16) short sPt[4][4096];
    int win = blockIdx.x, head = blockIdx.y;
    int iy = win / 12, ix = win % 12;
    int tid = threadIdx.x;
    int w = tid >> 6, lane = tid & 63;
    int m = lane & 15, h = lane >> 4;

    const unsigned short* Qp = qkv + (size_t)head * M_TOK * 32;
    const unsigned short* Kp = qkv + (size_t)(6 + head) * M_TOK * 32;

    short8 qf[4];
    #pragma unroll
    for (int i = 0; i < 4; i++) {
        int wy = w * 4 + i;
        size_t tok = (size_t)(iy * 16 + wy) * HW + ix * 16 + m;
        qf[i] = *(const short8*)&Qp[tok * 32 + h * 8];
    }

    short ob = (m == 0) ? (short)0x3F80 : (short)0;
    short8 bones = {ob, ob, ob, ob, ob, ob, ob, ob};

    floatx4 oacc[4][2];
    floatx4 lacc[4];
    #pragma unroll
    for (int i = 0; i < 4; i++) {
        lacc[i] = (floatx4){0.f, 0.f, 0.f, 0.f};
        oacc[i][0] = (floatx4){0.f, 0.f, 0.f, 0.f};
        oacc[i][1] = (floatx4){0.f, 0.f, 0.f, 0.f};
    }

    int skey = tid >> 2, dq = tid & 3;
    short* kdst = &sK[0][skey * 36 + dq * 8];
    short* vdst = &sV[0][(dq >> 1) * 1024 + (skey >> 2) * 64 + (skey & 3) * 16 + (dq & 1) * 8];

    auto fetch = [&](int c, short8& kv, short8& vv) {
        int key = c * 64 + skey;
        int oy = key / 24, ox = key - (key / 24) * 24;
        int gy = iy * 16 - 4 + oy, gx = ix * 16 - 4 + ox;
        kv = (short8){0,0,0,0,0,0,0,0};
        vv = (short8){0,0,0,0,0,0,0,0};
        if (gy >= 0 && gy < HW && gx >= 0 && gx < HW) {
            const unsigned short* p = &Kp[((size_t)gy * HW + gx) * 32 + dq * 8];
            kv = *(const short8*)p;
            vv = *(const short8*)(p + 6 * M_TOK * 32);
        }
    };

    {   // stage chunk 0 into buffer 0
        short8 kv, vv;
        fetch(0, kv, vv);
        *(short8*)kdst = kv;
        *(short8*)vdst = vv;
    }

    unsigned sPbase = (unsigned)(uintptr_t)&sPt[w][0];
    unsigned sPa = sPbase + 8 * m + 256 * h;
    unsigned sVa0 = (unsigned)(uintptr_t)&sV[0][0] + 8 * m + 256 * h;
    char* sPwb = (char*)&sPt[w][0] + 128 * (m >> 2) + 32 * (m & 3) + 8 * h;

    for (int c = 0; c < 9; c++) {
        __syncthreads();
        int cur = c & 1;
        short8 knx, vnx;
        bool more = (c < 8);
        if (more) fetch(c + 1, knx, vnx);

        const short* sKc = sK[cur];
        short8 kfrag[4];
        #pragma unroll
        for (int kt = 0; kt < 4; kt++)
            kfrag[kt] = *(const short8*)&sKc[(kt * 16 + m) * 36 + h * 8];

        const unsigned short* bb = btf + ((((size_t)head * 16 + w * 4) * 36 + c * 4) * 64 + lane) * 4;

        // ---- Phase A: QK + exp + P writes for all 4 q-tiles ----
        #pragma unroll
        for (int i = 0; i < 4; i++) {
            floatx4 s[4];
            #pragma unroll
            for (int kt = 0; kt < 4; kt++)
                s[kt] = bf4f(*(const s16x4*)&bb[(size_t)(i * 36 + kt) * 256]);
            __builtin_amdgcn_s_setprio(1);
            #pragma unroll
            for (int kt = 0; kt < 4; kt++)
                s[kt] = mfma16(qf[i], kfrag[kt], s[kt]);
            __builtin_amdgcn_s_setprio(0);
            #pragma unroll
            for (int kt = 0; kt < 4; kt++) {
                s16x4 pk;
                #pragma unroll
                for (int r = 0; r < 4; r++)
                    pk[r] = f2bfh(exp2fast(s[kt][r]));
                *(s16x4*)(sPwb + i * 2048 + kt * 512) = pk;
            }
        }

        // ---- Phase B: pipelined tr reads + PV ----
        unsigned sVa = sVa0 + cur * 4096;
        short8 vb[4];
        {
            s16x4 lo0 = tr16<0>(sVa),    hi0 = tr16<128>(sVa);
            s16x4 lo1 = tr16<2048>(sVa), hi1 = tr16<2176>(sVa);
            s16x4 lo2 = tr16<1024>(sVa), hi2 = tr16<1152>(sVa);
            s16x4 lo3 = tr16<3072>(sVa), hi3 = tr16<3200>(sVa);
            vb[0] = cat8(lo0, hi0);
            vb[1] = cat8(lo1, hi1);
            vb[2] = cat8(lo2, hi2);
            vb[3] = cat8(lo3, hi3);
        }
        s16x4 pl0 = tr16m<0>(sPa),    ph0 = tr16m<128>(sPa);
        s16x4 pl1 = tr16m<1024>(sPa), ph1 = tr16m<1152>(sPa);
        #pragma unroll
        for (int i = 0; i < 4; i++) {
            s16x4 nl0, nh0, nl1, nh1;
            if (i < 3) {
                unsigned a = sPa + (unsigned)((i + 1) * 2048);
                nl0 = tr16m<0>(a);    nh0 = tr16m<128>(a);
                nl1 = tr16m<1024>(a); nh1 = tr16m<1152>(a);
                wait_lgkm<4>();
            } else {
                wait_lgkm<0>();
            }
            __builtin_amdgcn_sched_barrier(0);
            short8 pa0 = cat8(pl0, ph0);
            short8 pa1 = cat8(pl1, ph1);
            __builtin_amdgcn_s_setprio(1);
            oacc[i][0] = mfma16(pa0, vb[0], oacc[i][0]);
            oacc[i][1] = mfma16(pa0, vb[1], oacc[i][1]);
            oacc[i][0] = mfma16(pa1, vb[2], oacc[i][0]);
            oacc[i][1] = mfma16(pa1, vb[3], oacc[i][1]);
            lacc[i] = mfma16(pa0, bones, lacc[i]);
            lacc[i] = mfma16(pa1, bones, lacc[i]);
            __builtin_amdgcn_s_setprio(0);
            if (i < 3) { pl0 = nl0; ph0 = nh0; pl1 = nl1; ph1 = nh1; }
        }

        if (more) {
            int nb = 1 - cur;
            *(short8*)(kdst + nb * 2304) = knx;
            *(short8*)(vdst + nb * 2048) = vnx;
        }
    }

    unsigned short* Op = out + (size_t)head * M_TOK * 32;
    #pragma unroll
    for (int i = 0; i < 4; i++) {
        float inv[4];
        #pragma unroll
        for (int r = 0; r < 4; r++) {
            float sum = __shfl(lacc[i][r], lane & 48);
            inv[r] = 1.f / sum;
        }
        int wy = w * 4 + i;
        #pragma unroll
        for (int dt = 0; dt < 2; dt++)
            #pragma unroll
            for (int r = 0; r < 4; r++) {
                size_t tok = (size_t)(iy * 16 + wy) * HW + ix * 16 + h * 4 + r;
                Op[tok * 32 + dt * 16 + m] = f2bf(oacc[i][dt][r] * inv[r]);
            }
    }
}

extern "C" void kernel_launch(void* const* d_in, const int* in_sizes, int n_in,
                              void* d_out, int out_size, void* d_ws, size_t ws_size,
                              hipStream_t stream) {
    const float* x     = (const float*)d_in[0];
    const int*   rpi   = (const int*)d_in[1];
    const float* n1g   = (const float*)d_in[4];
    const float* n1b   = (const float*)d_in[5];
    const float* qkvw  = (const float*)d_in[6];
    const float* qkvb  = (const float*)d_in[7];
    const float* rpb   = (const float*)d_in[8];
    const float* projw = (const float*)d_in[9];
    const float* projb = (const float*)d_in[10];
    const float* n2g   = (const float*)d_in[11];
    const float* n2b   = (const float*)d_in[12];
    const float* fc1w  = (const float*)d_in[13];
    const float* fc1b  = (const float*)d_in[14];
    const float* fc2w  = (const float*)d_in[15];
    const float* fc2b  = (const float*)d_in[16];

    char* ws = (char*)d_ws;
    unsigned short* wt_qkv  = (unsigned short*)ws;          // 110592 elems
    unsigned short* wt_proj = wt_qkv + 110592;              // 36864
    unsigned short* wt_fc1  = wt_proj + 36864;              // 73728
    unsigned short* wt_fc2  = wt_fc1 + 73728;               // 73728
    unsigned short* btf     = (unsigned short*)(ws + 589824);    // 884736 bf16
    unsigned short* xn      = (unsigned short*)(ws + 4128768);   // 36864*192 bf16
    unsigned short* qkv     = (unsigned short*)(ws + 18284544);  // planar [18][36864][32]
    unsigned short* attn_o  = (unsigned short*)(ws + 60751872);  // planar [6][36864][32]

    prep_kernel<<<9648, 256, 0, stream>>>(qkvw, x, n1g, n1b, wt_qkv, xn);
    gemm_kernel<0, 192><<<dim3(288, 15), 256, 0, stream>>>(
        xn, wt_qkv, qkvb, qkv, 576,
        rpi, rpb, btf, projw, fc1w, fc2w, wt_proj, wt_fc1, wt_fc2);
    attn_mfma_kernel<<<dim3(144, 6), 256, 0, stream>>>(qkv, btf, attn_o);
    mega_kernel<<<576, 256, 0, stream>>>(
        attn_o, wt_proj, wt_fc1, wt_fc2, projb, fc1b, fc2b,
        x, n2g, n2b, (float*)d_out);
}